// Round 1
// baseline (597.090 us; speedup 1.0000x reference)
//
#include <hip/hip_runtime.h>

#define HSZ 32
#define TT  1024

__device__ __forceinline__ float frcp(float x) { return __builtin_amdgcn_rcpf(x); }
__device__ __forceinline__ float sigm(float z) { return frcp(1.0f + __expf(-z)); }
__device__ __forceinline__ float tanhf_(float z) {
  z = fminf(fmaxf(z, -15.0f), 15.0f);
  float e = __expf(-2.0f * z);
  return (1.0f - e) * frcp(1.0f + e);
}

// 256 threads = 4 waves; each wave handles 2 batch elements (32 lanes each).
// Lane j of a 32-lane group owns hidden unit j: keeps W_hh rows j, 32+j, 64+j,
// 96+j in registers (128 VGPRs), the replicated h vector (32 VGPRs), and c_j.
__global__ __launch_bounds__(256, 2)
void lstm_fused_kernel(const float* __restrict__ x,
                       const float* __restrict__ W_ih,
                       const float* __restrict__ W_hh,
                       const float* __restrict__ b_ih,
                       const float* __restrict__ b_hh,
                       const float* __restrict__ W1, const float* __restrict__ b1,
                       const float* __restrict__ W2, const float* __restrict__ b2,
                       const float* __restrict__ W3, const float* __restrict__ b3,
                       float* __restrict__ out)
{
  __shared__ __align__(16) float hlds[8][HSZ];

  const int tid  = threadIdx.x;
  const int wave = tid >> 6;
  const int lane = tid & 63;
  const int grp  = lane >> 5;
  const int j    = lane & 31;
  const int we   = wave * 2 + grp;          // 0..7 within block
  const int elem = blockIdx.x * 8 + we;     // batch element

  // ---- load per-lane weight rows (gate order: i, f, g, o) ----
  float w0[HSZ], w1[HSZ], w2[HSZ], w3[HSZ];
  {
    const float4* r0 = reinterpret_cast<const float4*>(W_hh + (0 * 32 + j) * HSZ);
    const float4* r1 = reinterpret_cast<const float4*>(W_hh + (1 * 32 + j) * HSZ);
    const float4* r2 = reinterpret_cast<const float4*>(W_hh + (2 * 32 + j) * HSZ);
    const float4* r3 = reinterpret_cast<const float4*>(W_hh + (3 * 32 + j) * HSZ);
#pragma unroll
    for (int k4 = 0; k4 < 8; ++k4) {
      float4 a = r0[k4]; w0[4*k4+0]=a.x; w0[4*k4+1]=a.y; w0[4*k4+2]=a.z; w0[4*k4+3]=a.w;
      float4 b = r1[k4]; w1[4*k4+0]=b.x; w1[4*k4+1]=b.y; w1[4*k4+2]=b.z; w1[4*k4+3]=b.w;
      float4 c4= r2[k4]; w2[4*k4+0]=c4.x;w2[4*k4+1]=c4.y;w2[4*k4+2]=c4.z;w2[4*k4+3]=c4.w;
      float4 d = r3[k4]; w3[4*k4+0]=d.x; w3[4*k4+1]=d.y; w3[4*k4+2]=d.z; w3[4*k4+3]=d.w;
    }
  }
  const float bi0 = b_ih[0 * 32 + j] + b_hh[0 * 32 + j];
  const float bi1 = b_ih[1 * 32 + j] + b_hh[1 * 32 + j];
  const float bi2 = b_ih[2 * 32 + j] + b_hh[2 * 32 + j];
  const float bi3 = b_ih[3 * 32 + j] + b_hh[3 * 32 + j];
  const float wx0 = W_ih[0 * 32 + j];   // I == 1
  const float wx1 = W_ih[1 * 32 + j];
  const float wx2 = W_ih[2 * 32 + j];
  const float wx3 = W_ih[3 * 32 + j];

  float h[HSZ];
#pragma unroll
  for (int k = 0; k < HSZ; ++k) h[k] = 0.0f;
  float c = 0.0f;

  const float* xrow = x + (size_t)elem * TT;

#pragma unroll 1
  for (int t0 = 0; t0 < TT; t0 += 32) {
    float xc = xrow[t0 + j];                 // coalesced chunk of 32 timesteps
#pragma unroll 1
    for (int s = 0; s < 32; ++s) {
      float xt = __shfl(xc, s, 32);          // broadcast x_t within 32-lane group
      float a0 = fmaf(xt, wx0, bi0);
      float a1 = fmaf(xt, wx1, bi1);
      float a2 = fmaf(xt, wx2, bi2);
      float a3 = fmaf(xt, wx3, bi3);
#pragma unroll
      for (int k = 0; k < HSZ; ++k) {
        a0 = fmaf(w0[k], h[k], a0);
        a1 = fmaf(w1[k], h[k], a1);
        a2 = fmaf(w2[k], h[k], a2);
        a3 = fmaf(w3[k], h[k], a3);
      }
      float si = sigm(a0);
      float sf = sigm(a1);
      float tg = tanhf_(a2);
      float so = sigm(a3);
      c = fmaf(sf, c, si * tg);
      float hj = so * tanhf_(c);

      // broadcast new h across the 32-lane group via LDS (wave-synchronous,
      // in-order DS pipe: no barrier needed, waves own disjoint rows)
      hlds[we][j] = hj;
#pragma unroll
      for (int k4 = 0; k4 < 8; ++k4) {
        float4 v = *reinterpret_cast<const float4*>(&hlds[we][4 * k4]);
        h[4*k4+0] = v.x; h[4*k4+1] = v.y; h[4*k4+2] = v.z; h[4*k4+3] = v.w;
      }
    }
  }

  // ---- MLP head: 32 -> 16 -> 8 -> 1, computed redundantly per lane (h is
  // replicated); weight addresses are wave-uniform -> scalar loads ----
  float a1v[16];
#pragma unroll
  for (int r = 0; r < 16; ++r) {
    float acc = b1[r];
#pragma unroll
    for (int k = 0; k < 32; ++k) acc = fmaf(W1[r * 32 + k], h[k], acc);
    a1v[r] = fmaxf(acc, 0.0f);
  }
  float a2v[8];
#pragma unroll
  for (int r = 0; r < 8; ++r) {
    float acc = b2[r];
#pragma unroll
    for (int k = 0; k < 16; ++k) acc = fmaf(W2[r * 16 + k], a1v[k], acc);
    a2v[r] = fmaxf(acc, 0.0f);
  }
  float o = b3[0];
#pragma unroll
  for (int k = 0; k < 8; ++k) o = fmaf(W3[k], a2v[k], o);

  if (j == 0) out[elem] = o;
}

extern "C" void kernel_launch(void* const* d_in, const int* in_sizes, int n_in,
                              void* d_out, int out_size, void* d_ws, size_t ws_size,
                              hipStream_t stream) {
  const float* x    = (const float*)d_in[0];
  const float* W_ih = (const float*)d_in[1];
  const float* W_hh = (const float*)d_in[2];
  const float* b_ih = (const float*)d_in[3];
  const float* b_hh = (const float*)d_in[4];
  const float* W1   = (const float*)d_in[5];
  const float* b1   = (const float*)d_in[6];
  const float* W2   = (const float*)d_in[7];
  const float* b2   = (const float*)d_in[8];
  const float* W3   = (const float*)d_in[9];
  const float* b3   = (const float*)d_in[10];
  float* out = (float*)d_out;

  const int B = in_sizes[0] / TT;           // 4096
  dim3 grid(B / 8), block(256);             // 8 elements per block
  hipLaunchKernelGGL(lstm_fused_kernel, grid, block, 0, stream,
                     x, W_ih, W_hh, b_ih, b_hh, W1, b1, W2, b2, W3, b3, out);
}